// Round 1
// baseline (280.116 us; speedup 1.0000x reference)
//
#include <hip/hip_runtime.h>

// Problem constants (from reference): B=16, S=4096, H=768, T=2000
#define BB 16
#define SS 4096
#define HH 768
#define TT 2000
#define HV (HH / 4)   // 192 float4 per row

// ---------------------------------------------------------------------------
// Kernel 1: per-batch exclusive prefix sum of subtoken_lengths, +1 offset.
// starts[b,t] = 1 + sum_{t'<t} len[b,t']
// One block per batch, 256 threads, 8 lengths per thread (256*8=2048 >= 2000).
// ---------------------------------------------------------------------------
__global__ __launch_bounds__(256) void tokrep_scan_kernel(
    const int* __restrict__ lens, int* __restrict__ starts) {
    __shared__ int sums[256];
    const int b = blockIdx.x;
    const int tid = threadIdx.x;
    const int PER = 8;
    const int base_t = tid * PER;

    int local[PER];
    int s = 0;
#pragma unroll
    for (int i = 0; i < PER; ++i) {
        int t = base_t + i;
        int v = (t < TT) ? lens[b * TT + t] : 0;
        local[i] = s;  // exclusive prefix within this thread's chunk
        s += v;
    }
    sums[tid] = s;
    __syncthreads();

    // Hillis-Steele inclusive scan over the 256 chunk sums
    for (int off = 1; off < 256; off <<= 1) {
        int v = (tid >= off) ? sums[tid - off] : 0;
        __syncthreads();
        if (tid >= off) sums[tid] += v;
        __syncthreads();
    }
    const int chunk_base = (tid == 0) ? 0 : sums[tid - 1];

#pragma unroll
    for (int i = 0; i < PER; ++i) {
        int t = base_t + i;
        if (t < TT) starts[b * TT + t] = 1 + chunk_base + local[i];
    }
}

// ---------------------------------------------------------------------------
// Kernel 2: pooled[b,t,:] = len==0 ? 0 : mean(hidden[b, start:start+len, :])
// One float4 per thread; 192 consecutive threads cover one token's row, so
// global reads/writes are coalesced and the len-branch is near wave-uniform.
// ---------------------------------------------------------------------------
__global__ __launch_bounds__(256) void tokrep_pool_kernel(
    const float4* __restrict__ hs, const int* __restrict__ lens,
    const int* __restrict__ starts, float4* __restrict__ out) {
    const int idx = blockIdx.x * blockDim.x + threadIdx.x;   // < B*T*HV
    const int bt = idx / HV;
    const int h  = idx - bt * HV;
    const int b  = bt / TT;

    const int len   = lens[bt];
    const int start = starts[bt];

    // (b*S + start) <= 16*4096, *HV <= ~12.6M float4 -> fits int
    const float4* row = hs + (size_t)(b * SS + start) * HV + h;

    float4 r;
    if (len == 1) {
        r = row[0];
    } else if (len == 2) {
        float4 a = row[0];
        float4 c = row[HV];
        r.x = (a.x + c.x) * 0.5f;
        r.y = (a.y + c.y) * 0.5f;
        r.z = (a.z + c.z) * 0.5f;
        r.w = (a.w + c.w) * 0.5f;
    } else {
        r = make_float4(0.f, 0.f, 0.f, 0.f);
    }
    out[idx] = r;
}

// ---------------------------------------------------------------------------
extern "C" void kernel_launch(void* const* d_in, const int* in_sizes, int n_in,
                              void* d_out, int out_size, void* d_ws, size_t ws_size,
                              hipStream_t stream) {
    const float* hs  = (const float*)d_in[0];   // (B,S,H) fp32
    const int* lens  = (const int*)d_in[1];     // (B,T) int32
    float* out       = (float*)d_out;           // (B,T,H) fp32
    int* starts      = (int*)d_ws;              // B*T ints = 128 KB scratch

    tokrep_scan_kernel<<<BB, 256, 0, stream>>>(lens, starts);

    const int total_vec = BB * TT * HV;         // 6,144,000
    tokrep_pool_kernel<<<total_vec / 256, 256, 0, stream>>>(
        (const float4*)hs, lens, starts, (float4*)out);
}

// Round 3
// 274.016 us; speedup vs baseline: 1.0223x; 1.0223x over previous
//
#include <hip/hip_runtime.h>

// Problem constants (from reference): B=16, S=4096, H=768, T=2000
#define BB 16
#define SS 4096
#define HH 768
#define TT 2000
#define HV (HH / 4)   // 192 float4 per row

// clang-native 4-float vector: required by __builtin_nontemporal_{load,store}
typedef float vf4 __attribute__((ext_vector_type(4)));

// ---------------------------------------------------------------------------
// Kernel 1: per-batch exclusive prefix sum of subtoken_lengths, +1 offset.
// starts[b,t] = 1 + sum_{t'<t} len[b,t']
// One block per batch; 250 active threads x 8 lengths (2 x int4) = 2000 exact.
// ---------------------------------------------------------------------------
__global__ __launch_bounds__(256) void tokrep_scan_kernel(
    const int4* __restrict__ lens4, int* __restrict__ starts) {
    __shared__ int sums[256];
    const int b = blockIdx.x;
    const int tid = threadIdx.x;

    int v[8];
    int s = 0;
    if (tid < 250) {
        int4 a = lens4[b * 500 + tid * 2];
        int4 c = lens4[b * 500 + tid * 2 + 1];
        v[0] = a.x; v[1] = a.y; v[2] = a.z; v[3] = a.w;
        v[4] = c.x; v[5] = c.y; v[6] = c.z; v[7] = c.w;
#pragma unroll
        for (int i = 0; i < 8; ++i) { int t = v[i]; v[i] = s; s += t; }
    }
    sums[tid] = s;
    __syncthreads();

    // Hillis-Steele inclusive scan over the 256 chunk sums
    for (int off = 1; off < 256; off <<= 1) {
        int x = (tid >= off) ? sums[tid - off] : 0;
        __syncthreads();
        if (tid >= off) sums[tid] += x;
        __syncthreads();
    }

    if (tid < 250) {
        const int base = 1 + ((tid == 0) ? 0 : sums[tid - 1]);
        int4 o0 = make_int4(base + v[0], base + v[1], base + v[2], base + v[3]);
        int4 o1 = make_int4(base + v[4], base + v[5], base + v[6], base + v[7]);
        int4* st4 = (int4*)(starts + b * TT);   // b*2000*4 bytes: 16B aligned
        st4[tid * 2]     = o0;
        st4[tid * 2 + 1] = o1;
    }
}

// ---------------------------------------------------------------------------
// Kernel 2: pooled[b,t,:] = len==0 ? 0 : mean(hidden[b, start:start+len, :])
// grid = (T/2, B), block = (192, 2): threadIdx.x = h (float4 lane),
// threadIdx.y selects which of the block's 2 tokens. Every 64-lane wave has a
// single token -> wave-uniform len branch, no integer division anywhere.
// Streaming loads/stores are nontemporal to keep L2 for the lens/starts.
// ---------------------------------------------------------------------------
__global__ __launch_bounds__(384) void tokrep_pool_kernel(
    const vf4* __restrict__ hs, const int* __restrict__ lens,
    const int* __restrict__ starts, vf4* __restrict__ out) {
    const int t  = blockIdx.x * 2 + threadIdx.y;
    const int b  = blockIdx.y;
    const int bt = b * TT + t;
    const int h  = threadIdx.x;

    const int len   = lens[bt];
    const int start = starts[bt];

    const vf4* row = hs + (size_t)(b * SS + start) * HV + h;

    vf4 r = (vf4)(0.f);
    if (len == 1) {
        r = __builtin_nontemporal_load(row);
    } else if (len == 2) {
        vf4 a = __builtin_nontemporal_load(row);
        vf4 c = __builtin_nontemporal_load(row + HV);
        r = (a + c) * 0.5f;
    }
    __builtin_nontemporal_store(r, out + (size_t)bt * HV + h);
}

// ---------------------------------------------------------------------------
extern "C" void kernel_launch(void* const* d_in, const int* in_sizes, int n_in,
                              void* d_out, int out_size, void* d_ws, size_t ws_size,
                              hipStream_t stream) {
    const float* hs  = (const float*)d_in[0];   // (B,S,H) fp32
    const int* lens  = (const int*)d_in[1];     // (B,T) int32
    float* out       = (float*)d_out;           // (B,T,H) fp32
    int* starts      = (int*)d_ws;              // B*T ints = 128 KB scratch

    tokrep_scan_kernel<<<BB, 256, 0, stream>>>((const int4*)lens, starts);

    dim3 grid(TT / 2, BB);       // (1000, 16)
    dim3 block(HV, 2);           // (192, 2) = 384 threads, 6 waves
    tokrep_pool_kernel<<<grid, block, 0, stream>>>(
        (const vf4*)hs, lens, starts, (vf4*)out);
}